// Round 1
// baseline (4350.873 us; speedup 1.0000x reference)
//
#include <hip/hip_runtime.h>
#include <cstdint>

#define B_   128
#define L_   512
#define E_   512
#define H_   8
#define HD_  64
#define NB_  2
#define WIN_ 64
#define NROW (B_ * L_)  // 65536

typedef __attribute__((ext_vector_type(8))) __bf16 bf16x8;
typedef __attribute__((ext_vector_type(4))) float f32x4;

static __device__ __forceinline__ unsigned short f2bf(float f) {
  union { float f; unsigned int u; } c; c.f = f;
  unsigned int u = c.u;
  unsigned int r = (u + 0x7fffu + ((u >> 16) & 1u)) >> 16;
  return (unsigned short)r;
}
static __device__ __forceinline__ float bflo(unsigned int w) {
  union { unsigned int u; float f; } c; c.u = w << 16; return c.f;
}
static __device__ __forceinline__ float bfhi(unsigned int w) {
  union { unsigned int u; float f; } c; c.u = w & 0xffff0000u; return c.f;
}

static __device__ __forceinline__ void gld_lds16(const unsigned short* g, unsigned short* l) {
  __builtin_amdgcn_global_load_lds((const __attribute__((address_space(1))) void*)g,
                                   (__attribute__((address_space(3))) void*)l, 16, 0, 0);
}

// ---------------- mask dtype detection (bool-bytes vs int32) ----------------
__global__ void detect_mask_kernel(const unsigned char* tm, int* flag) {
  __shared__ int f;
  if (threadIdx.x == 0) f = 0;
  __syncthreads();
  int local = 0;
  for (int i = threadIdx.x; i < NROW; i += blockDim.x)
    if ((i & 3) && tm[i]) local = 1;
  if (local) atomicOr(&f, 1);
  __syncthreads();
  if (threadIdx.x == 0) *flag = f;  // 1 => uint8 bytes, 0 => int32
}

__global__ void expand_keep_kernel(const void* tmv, const int* flag, float* keepF) {
  int i = blockIdx.x * blockDim.x + threadIdx.x;
  if (i >= NROW) return;
  int m;
  if (*flag) m = ((const unsigned char*)tmv)[i] != 0;
  else       m = ((const int*)tmv)[i] != 0;
  keepF[i] = m ? 0.f : 1.f;
}

// ---------------- fp32 -> bf16 weight conversion ----------------
__global__ void f2bf_kernel(const float* __restrict__ in, unsigned short* __restrict__ out, int n) {
  int i = blockIdx.x * blockDim.x + threadIdx.x;
  if (i < n) out[i] = f2bf(in[i]);
}

// ---------------- x = seqs * keep (writes fp32 + bf16) ----------------
__global__ void mask_kernel(const float* __restrict__ seqs, const float* __restrict__ keepF,
                            float* xF, unsigned short* xB) {
  int i = blockIdx.x * blockDim.x + threadIdx.x;  // group of 4 elements
  int idx = i * 4;
  int row = idx >> 9;  // / E_
  float k = keepF[row];
  float4 v = *(const float4*)(seqs + idx);
  v.x *= k; v.y *= k; v.z *= k; v.w *= k;
  *(float4*)(xF + idx) = v;
  ushort4 b;
  b.x = f2bf(v.x); b.y = f2bf(v.y); b.z = f2bf(v.z); b.w = f2bf(v.w);
  *(ushort4*)(xB + idx) = b;
}

// ---------------- LayerNorm over E=512, one wave per row ----------------
__global__ __launch_bounds__(256) void ln_kernel(const float* X,
                                                 const float* __restrict__ g,
                                                 const float* __restrict__ bb,
                                                 float* outF, unsigned short* outB) {
  int wave = threadIdx.x >> 6, lane = threadIdx.x & 63;
  size_t row = (size_t)blockIdx.x * 4 + wave;
  const float* xr = X + row * E_;
  int e0 = lane * 4, e1 = 256 + lane * 4;
  float4 a = *(const float4*)(xr + e0);
  float4 c = *(const float4*)(xr + e1);
  float s  = a.x + a.y + a.z + a.w + c.x + c.y + c.z + c.w;
  float s2 = a.x*a.x + a.y*a.y + a.z*a.z + a.w*a.w + c.x*c.x + c.y*c.y + c.z*c.z + c.w*c.w;
  for (int off = 32; off; off >>= 1) { s += __shfl_xor(s, off); s2 += __shfl_xor(s2, off); }
  float mean = s * (1.f / E_);
  float var  = s2 * (1.f / E_) - mean * mean;
  float rs = rsqrtf(var + 1e-8f);
  float4 g0 = *(const float4*)(g + e0),  g1 = *(const float4*)(g + e1);
  float4 b0 = *(const float4*)(bb + e0), b1 = *(const float4*)(bb + e1);
  float4 y0, y1;
  y0.x = (a.x - mean) * rs * g0.x + b0.x;
  y0.y = (a.y - mean) * rs * g0.y + b0.y;
  y0.z = (a.z - mean) * rs * g0.z + b0.z;
  y0.w = (a.w - mean) * rs * g0.w + b0.w;
  y1.x = (c.x - mean) * rs * g1.x + b1.x;
  y1.y = (c.y - mean) * rs * g1.y + b1.y;
  y1.z = (c.z - mean) * rs * g1.z + b1.z;
  y1.w = (c.w - mean) * rs * g1.w + b1.w;
  if (outF) {
    *(float4*)(outF + row * E_ + e0) = y0;
    *(float4*)(outF + row * E_ + e1) = y1;
  }
  if (outB) {
    ushort4 p0, p1;
    p0.x = f2bf(y0.x); p0.y = f2bf(y0.y); p0.z = f2bf(y0.z); p0.w = f2bf(y0.w);
    p1.x = f2bf(y1.x); p1.y = f2bf(y1.y); p1.z = f2bf(y1.z); p1.w = f2bf(y1.w);
    *(ushort4*)(outB + row * E_ + e0) = p0;
    *(ushort4*)(outB + row * E_ + e1) = p1;
  }
}

// ---------------- bf16 MFMA GEMM: C[N x M] = A[N x K] @ W[M x K]^T + epilogue ----
// m97 structure: 128x128 tile, BK=32, global_load_lds width 16, 4 waves 2x2.
__global__ __launch_bounds__(256) void gemm_kernel(
    const unsigned short* __restrict__ A, const unsigned short* __restrict__ W,
    const float* __restrict__ bias, const float* res, const float* __restrict__ keepF,
    float* outF, unsigned short* outB, int K, int M, int relu) {
  __shared__ unsigned short sA[128 * 32];
  __shared__ unsigned short sW[128 * 32];
  int tid = threadIdx.x;
  int wave = tid >> 6, lane = tid & 63;
  int lm = lane & 15, quad = lane >> 4;
  size_t row0 = (size_t)blockIdx.y * 128;
  int col0 = blockIdx.x * 128;
  int wm = (wave >> 1) * 64, wn = (wave & 1) * 64;

  f32x4 acc[4][4];
  f32x4 z = {0.f, 0.f, 0.f, 0.f};
#pragma unroll
  for (int i = 0; i < 4; ++i)
#pragma unroll
    for (int j = 0; j < 4; ++j) acc[i][j] = z;

  int c0 = tid, c1 = tid + 256;
  int ar0 = c0 >> 2, ak0 = (c0 & 3) * 8;
  int ar1 = c1 >> 2, ak1 = (c1 & 3) * 8;
  unsigned short* dA0 = &sA[(0 * 256 + wave * 64) * 8];
  unsigned short* dA1 = &sA[(1 * 256 + wave * 64) * 8];
  unsigned short* dW0 = &sW[(0 * 256 + wave * 64) * 8];
  unsigned short* dW1 = &sW[(1 * 256 + wave * 64) * 8];

  for (int k0 = 0; k0 < K; k0 += 32) {
    __syncthreads();
    gld_lds16(A + (row0 + ar0) * K + k0 + ak0, dA0);
    gld_lds16(A + (row0 + ar1) * K + k0 + ak1, dA1);
    gld_lds16(W + (size_t)(col0 + ar0) * K + k0 + ak0, dW0);
    gld_lds16(W + (size_t)(col0 + ar1) * K + k0 + ak1, dW1);
    __syncthreads();
    bf16x8 af[4], bf[4];
#pragma unroll
    for (int mt = 0; mt < 4; ++mt)
      af[mt] = *(const bf16x8*)&sA[(wm + mt * 16 + lm) * 32 + quad * 8];
#pragma unroll
    for (int nt = 0; nt < 4; ++nt)
      bf[nt] = *(const bf16x8*)&sW[(wn + nt * 16 + lm) * 32 + quad * 8];
#pragma unroll
    for (int mt = 0; mt < 4; ++mt)
#pragma unroll
      for (int nt = 0; nt < 4; ++nt)
        acc[mt][nt] = __builtin_amdgcn_mfma_f32_16x16x32_bf16(af[mt], bf[nt], acc[mt][nt], 0, 0, 0);
  }

#pragma unroll
  for (int mt = 0; mt < 4; ++mt) {
#pragma unroll
    for (int r = 0; r < 4; ++r) {
      size_t row = row0 + wm + mt * 16 + quad * 4 + r;
      float kf = keepF ? keepF[row] : 1.f;
#pragma unroll
      for (int nt = 0; nt < 4; ++nt) {
        int col = col0 + wn + nt * 16 + lm;
        float v = acc[mt][nt][r] + bias[col];
        if (res) v += res[row * M + col];
        if (relu) v = fmaxf(v, 0.f);
        v *= kf;
        if (outF) outF[row * M + col] = v;
        if (outB) outB[row * M + col] = f2bf(v);
      }
    }
  }
}

// ---------------- sliding-window attention (bf16 in/out, fp32 math) ----------------
// grid (L/64, H, B), block 256. O may alias Q (block reads its own Q tile only).
__global__ __launch_bounds__(256) void attn_kernel(const unsigned short* Q,
                                                   const unsigned short* __restrict__ K,
                                                   const unsigned short* __restrict__ V,
                                                   unsigned short* O) {
  __shared__ unsigned int sQ[64 * 33];
  __shared__ unsigned int sK[128 * 33];
  __shared__ unsigned int sV[128 * 33];
  __shared__ float sS[64 * 65];
  int i0 = blockIdx.x * 64;
  int h = blockIdx.y;
  int b = blockIdx.z;
  int tid = threadIdx.x;
  size_t base = ((size_t)b * L_) * E_ + h * 64;

  for (int f = tid; f < 64 * 32; f += 256) {
    int r = f >> 5, c = f & 31;
    sQ[r * 33 + c] = *(const unsigned int*)&Q[base + (size_t)(i0 + r) * E_ + c * 2];
  }
  for (int f = tid; f < 128 * 32; f += 256) {
    int r = f >> 5, c = f & 31;
    int j = i0 - 64 + r;
    unsigned int kw = 0, vw = 0;
    if (j >= 0) {
      kw = *(const unsigned int*)&K[base + (size_t)j * E_ + c * 2];
      vw = *(const unsigned int*)&V[base + (size_t)j * E_ + c * 2];
    }
    sK[r * 33 + c] = kw;
    sV[r * 33 + c] = vw;
  }
  __syncthreads();

  int wave = tid >> 6, lane = tid & 63;
  // phase 1: scores
  for (int it = 0; it < 16; ++it) {
    int qi = wave * 16 + it;
    int j = i0 + qi - 63 + lane;
    float s = -INFINITY;
    if (j >= 0) {
      int kr = qi + 1 + lane;
      const unsigned int* qrow = &sQ[qi * 33];
      const unsigned int* krow = &sK[kr * 33];
      float a = 0.f;
#pragma unroll 8
      for (int c = 0; c < 32; ++c) {
        unsigned int qw = qrow[c], kw = krow[c];
        a += bflo(qw) * bflo(kw) + bfhi(qw) * bfhi(kw);
      }
      s = a * 0.125f;  // 1/sqrt(HD)
    }
    sS[qi * 65 + lane] = s;
  }
  __syncthreads();
  // phase 2: softmax per query row
  for (int it = 0; it < 16; ++it) {
    int qi = wave * 16 + it;
    float s = sS[qi * 65 + lane];
    float m = s;
    for (int off = 32; off; off >>= 1) m = fmaxf(m, __shfl_xor(m, off));
    float e = __expf(s - m);
    float su = e;
    for (int off = 32; off; off >>= 1) su += __shfl_xor(su, off);
    sS[qi * 65 + lane] = e / su;
  }
  __syncthreads();
  // phase 3: O = P @ V
  for (int it = 0; it < 16; ++it) {
    int qi = wave * 16 + it;
    int d = lane;
    int wmin = 63 - i0 - qi; if (wmin < 0) wmin = 0;
    float a = 0.f;
    for (int w = wmin; w < 64; ++w) {
      float p = sS[qi * 65 + w];
      unsigned int vw = sV[(qi + 1 + w) * 33 + (d >> 1)];
      a += p * ((d & 1) ? bfhi(vw) : bflo(vw));
    }
    O[base + (size_t)(i0 + qi) * E_ + d] = f2bf(a);
  }
}

extern "C" void kernel_launch(void* const* d_in, const int* in_sizes, int n_in,
                              void* d_out, int out_size, void* d_ws, size_t ws_size,
                              hipStream_t stream) {
  const void*  tm    = d_in[0];
  const float* seqs  = (const float*)d_in[1];
  const float* w_in  = (const float*)d_in[2];
  const float* b_in  = (const float*)d_in[3];
  const float* w_out = (const float*)d_in[4];
  const float* b_out = (const float*)d_in[5];
  const float* ln1_g = (const float*)d_in[6];
  const float* ln1_b = (const float*)d_in[7];
  const float* ln2_g = (const float*)d_in[8];
  const float* ln2_b = (const float*)d_in[9];
  const float* c1_w  = (const float*)d_in[10];
  const float* c1_b  = (const float*)d_in[11];
  const float* c2_w  = (const float*)d_in[12];
  const float* c2_b  = (const float*)d_in[13];
  const float* lnf_g = (const float*)d_in[14];
  const float* lnf_b = (const float*)d_in[15];

  char* ws = (char*)d_ws;
  size_t off = 0;
  auto alloc = [&](size_t bytes) -> char* {
    char* p = ws + off;
    off += (bytes + 255) & ~(size_t)255;
    return p;
  };
  const size_t NE = (size_t)NROW * E_;
  float*          qin    = (float*)alloc(NE * 4);
  unsigned short* xb     = (unsigned short*)alloc(NE * 2);
  unsigned short* qinb   = (unsigned short*)alloc(NE * 2);
  unsigned short* qb     = (unsigned short*)alloc(NE * 2);
  unsigned short* kb     = (unsigned short*)alloc(NE * 2);
  unsigned short* vb     = (unsigned short*)alloc(NE * 2);
  unsigned short* w_in_b = (unsigned short*)alloc((size_t)NB_ * 3 * E_ * E_ * 2);
  unsigned short* w_out_b= (unsigned short*)alloc((size_t)NB_ * E_ * E_ * 2);
  unsigned short* wc1b   = (unsigned short*)alloc((size_t)NB_ * E_ * E_ * 2);
  unsigned short* wc2b   = (unsigned short*)alloc((size_t)NB_ * E_ * E_ * 2);
  float*          keepF  = (float*)alloc((size_t)NROW * 4);
  int*            flag   = (int*)alloc(256);
  if (off > ws_size) return;  // fail loudly (output stays poisoned)

  float* x = (float*)d_out;  // fp32 activation lives in d_out

  detect_mask_kernel<<<1, 256, 0, stream>>>((const unsigned char*)tm, flag);
  expand_keep_kernel<<<NROW / 256, 256, 0, stream>>>(tm, flag, keepF);

  int n_win = NB_ * 3 * E_ * E_, n_sq = NB_ * E_ * E_;
  f2bf_kernel<<<(n_win + 255) / 256, 256, 0, stream>>>(w_in, w_in_b, n_win);
  f2bf_kernel<<<(n_sq + 255) / 256, 256, 0, stream>>>(w_out, w_out_b, n_sq);
  f2bf_kernel<<<(n_sq + 255) / 256, 256, 0, stream>>>(c1_w, wc1b, n_sq);
  f2bf_kernel<<<(n_sq + 255) / 256, 256, 0, stream>>>(c2_w, wc2b, n_sq);

  mask_kernel<<<(int)(NE / 4 / 256), 256, 0, stream>>>(seqs, keepF, x, xb);

  dim3 ggrid(E_ / 128, NROW / 128);
  for (int blk = 0; blk < NB_; ++blk) {
    const unsigned short* wq = w_in_b + (size_t)blk * 3 * E_ * E_;
    const unsigned short* wk = wq + (size_t)E_ * E_;
    const unsigned short* wv = wq + (size_t)2 * E_ * E_;
    const float* bq = b_in + (size_t)blk * 3 * E_;
    const float* bk = bq + E_;
    const float* bv = bq + 2 * E_;

    // q_in = LN(x, ln1)
    ln_kernel<<<NROW / 4, 256, 0, stream>>>(x, ln1_g + blk * E_, ln1_b + blk * E_, qin, qinb);
    // q/k/v projections (bf16 out)
    gemm_kernel<<<ggrid, 256, 0, stream>>>(qinb, wq, bq, nullptr, nullptr, nullptr, qb, E_, E_, 0);
    gemm_kernel<<<ggrid, 256, 0, stream>>>(xb,   wk, bk, nullptr, nullptr, nullptr, kb, E_, E_, 0);
    gemm_kernel<<<ggrid, 256, 0, stream>>>(xb,   wv, bv, nullptr, nullptr, nullptr, vb, E_, E_, 0);
    // windowed attention, O overwrites qb
    attn_kernel<<<dim3(L_ / 64, H_, B_), 256, 0, stream>>>(qb, kb, vb, qb);
    // x = qin + attnO @ w_out^T + b_out  (fp32 into d_out)
    gemm_kernel<<<ggrid, 256, 0, stream>>>(qb, w_out_b + (size_t)blk * E_ * E_,
                                           b_out + blk * E_, qin, nullptr, x, nullptr, E_, E_, 0);
    // x = LN(x, ln2) in place + bf16 copy
    ln_kernel<<<NROW / 4, 256, 0, stream>>>(x, ln2_g + blk * E_, ln2_b + blk * E_, x, xb);
    // h = relu(x @ c1^T + b1)  (bf16 into kb)
    gemm_kernel<<<ggrid, 256, 0, stream>>>(xb, wc1b + (size_t)blk * E_ * E_,
                                           c1_b + blk * E_, nullptr, nullptr, nullptr, kb, E_, E_, 1);
    // x = (h @ c2^T + b2 + x) * keep   (fp32 into d_out, bf16 into xb)
    gemm_kernel<<<ggrid, 256, 0, stream>>>(kb, wc2b + (size_t)blk * E_ * E_,
                                           c2_b + blk * E_, x, keepF, x, xb, E_, E_, 0);
  }
  // final LN in place on d_out
  ln_kernel<<<NROW / 4, 256, 0, stream>>>(x, lnf_g, lnf_b, x, nullptr);
}

// Round 3
// 2139.898 us; speedup vs baseline: 2.0332x; 2.0332x over previous
//
#include <hip/hip_runtime.h>
#include <cstdint>

#define B_   128
#define L_   512
#define E_   512
#define H_   8
#define HD_  64
#define NB_  2
#define WIN_ 64
#define NROW (B_ * L_)  // 65536

typedef __attribute__((ext_vector_type(8))) __bf16 bf16x8;
typedef __attribute__((ext_vector_type(4))) float f32x4;

static __device__ __forceinline__ unsigned short f2bf(float f) {
  union { float f; unsigned int u; } c; c.f = f;
  unsigned int u = c.u;
  unsigned int r = (u + 0x7fffu + ((u >> 16) & 1u)) >> 16;
  return (unsigned short)r;
}

static __device__ __forceinline__ void gld_lds16(const unsigned short* g, unsigned short* l) {
  __builtin_amdgcn_global_load_lds((const __attribute__((address_space(1))) void*)g,
                                   (__attribute__((address_space(3))) void*)l, 16, 0, 0);
}

// ---------------- mask dtype detection (bool-bytes vs int32) ----------------
__global__ void detect_mask_kernel(const unsigned char* tm, int* flag) {
  __shared__ int f;
  if (threadIdx.x == 0) f = 0;
  __syncthreads();
  int local = 0;
  for (int i = threadIdx.x; i < NROW; i += blockDim.x)
    if ((i & 3) && tm[i]) local = 1;
  if (local) atomicOr(&f, 1);
  __syncthreads();
  if (threadIdx.x == 0) *flag = f;  // 1 => uint8 bytes, 0 => int32
}

__global__ void expand_keep_kernel(const void* tmv, const int* flag, float* keepF) {
  int i = blockIdx.x * blockDim.x + threadIdx.x;
  if (i >= NROW) return;
  int m;
  if (*flag) m = ((const unsigned char*)tmv)[i] != 0;
  else       m = ((const int*)tmv)[i] != 0;
  keepF[i] = m ? 0.f : 1.f;
}

// ---------------- fp32 -> bf16 weight conversion ----------------
__global__ void f2bf_kernel(const float* __restrict__ in, unsigned short* __restrict__ out, int n) {
  int i = blockIdx.x * blockDim.x + threadIdx.x;
  if (i < n) out[i] = f2bf(in[i]);
}

// ---------------- x = seqs * keep (writes fp32 + bf16) ----------------
__global__ void mask_kernel(const float* __restrict__ seqs, const float* __restrict__ keepF,
                            float* xF, unsigned short* xB) {
  int i = blockIdx.x * blockDim.x + threadIdx.x;  // group of 4 elements
  int idx = i * 4;
  int row = idx >> 9;  // / E_
  float k = keepF[row];
  float4 v = *(const float4*)(seqs + idx);
  v.x *= k; v.y *= k; v.z *= k; v.w *= k;
  *(float4*)(xF + idx) = v;
  ushort4 b;
  b.x = f2bf(v.x); b.y = f2bf(v.y); b.z = f2bf(v.z); b.w = f2bf(v.w);
  *(ushort4*)(xB + idx) = b;
}

// ---------------- LayerNorm over E=512, one wave per row ----------------
__global__ __launch_bounds__(256) void ln_kernel(const float* X,
                                                 const float* __restrict__ g,
                                                 const float* __restrict__ bb,
                                                 float* outF, unsigned short* outB) {
  int wave = threadIdx.x >> 6, lane = threadIdx.x & 63;
  size_t row = (size_t)blockIdx.x * 4 + wave;
  const float* xr = X + row * E_;
  int e0 = lane * 4, e1 = 256 + lane * 4;
  float4 a = *(const float4*)(xr + e0);
  float4 c = *(const float4*)(xr + e1);
  float s  = a.x + a.y + a.z + a.w + c.x + c.y + c.z + c.w;
  float s2 = a.x*a.x + a.y*a.y + a.z*a.z + a.w*a.w + c.x*c.x + c.y*c.y + c.z*c.z + c.w*c.w;
  for (int off = 32; off; off >>= 1) { s += __shfl_xor(s, off); s2 += __shfl_xor(s2, off); }
  float mean = s * (1.f / E_);
  float var  = s2 * (1.f / E_) - mean * mean;
  float rs = rsqrtf(var + 1e-8f);
  float4 g0 = *(const float4*)(g + e0),  g1 = *(const float4*)(g + e1);
  float4 b0 = *(const float4*)(bb + e0), b1 = *(const float4*)(bb + e1);
  float4 y0, y1;
  y0.x = (a.x - mean) * rs * g0.x + b0.x;
  y0.y = (a.y - mean) * rs * g0.y + b0.y;
  y0.z = (a.z - mean) * rs * g0.z + b0.z;
  y0.w = (a.w - mean) * rs * g0.w + b0.w;
  y1.x = (c.x - mean) * rs * g1.x + b1.x;
  y1.y = (c.y - mean) * rs * g1.y + b1.y;
  y1.z = (c.z - mean) * rs * g1.z + b1.z;
  y1.w = (c.w - mean) * rs * g1.w + b1.w;
  if (outF) {
    *(float4*)(outF + row * E_ + e0) = y0;
    *(float4*)(outF + row * E_ + e1) = y1;
  }
  if (outB) {
    ushort4 p0, p1;
    p0.x = f2bf(y0.x); p0.y = f2bf(y0.y); p0.z = f2bf(y0.z); p0.w = f2bf(y0.w);
    p1.x = f2bf(y1.x); p1.y = f2bf(y1.y); p1.z = f2bf(y1.z); p1.w = f2bf(y1.w);
    *(ushort4*)(outB + row * E_ + e0) = p0;
    *(ushort4*)(outB + row * E_ + e1) = p1;
  }
}

// ---------------- bf16 MFMA GEMM: C[N x M] = A[N x K] @ W[M x K]^T + epilogue ----
__global__ __launch_bounds__(256) void gemm_kernel(
    const unsigned short* __restrict__ A, const unsigned short* __restrict__ W,
    const float* __restrict__ bias, const float* res, const float* __restrict__ keepF,
    float* outF, unsigned short* outB, int K, int M, int relu) {
  __shared__ unsigned short sA[128 * 32];
  __shared__ unsigned short sW[128 * 32];
  int tid = threadIdx.x;
  int wave = tid >> 6, lane = tid & 63;
  int lm = lane & 15, quad = lane >> 4;
  size_t row0 = (size_t)blockIdx.y * 128;
  int col0 = blockIdx.x * 128;
  int wm = (wave >> 1) * 64, wn = (wave & 1) * 64;

  f32x4 acc[4][4];
  f32x4 z = {0.f, 0.f, 0.f, 0.f};
#pragma unroll
  for (int i = 0; i < 4; ++i)
#pragma unroll
    for (int j = 0; j < 4; ++j) acc[i][j] = z;

  int c0 = tid, c1 = tid + 256;
  int ar0 = c0 >> 2, ak0 = (c0 & 3) * 8;
  int ar1 = c1 >> 2, ak1 = (c1 & 3) * 8;
  unsigned short* dA0 = &sA[(0 * 256 + wave * 64) * 8];
  unsigned short* dA1 = &sA[(1 * 256 + wave * 64) * 8];
  unsigned short* dW0 = &sW[(0 * 256 + wave * 64) * 8];
  unsigned short* dW1 = &sW[(1 * 256 + wave * 64) * 8];

  for (int k0 = 0; k0 < K; k0 += 32) {
    __syncthreads();
    gld_lds16(A + (row0 + ar0) * K + k0 + ak0, dA0);
    gld_lds16(A + (row0 + ar1) * K + k0 + ak1, dA1);
    gld_lds16(W + (size_t)(col0 + ar0) * K + k0 + ak0, dW0);
    gld_lds16(W + (size_t)(col0 + ar1) * K + k0 + ak1, dW1);
    __syncthreads();
    bf16x8 af[4], bf[4];
#pragma unroll
    for (int mt = 0; mt < 4; ++mt)
      af[mt] = *(const bf16x8*)&sA[(wm + mt * 16 + lm) * 32 + quad * 8];
#pragma unroll
    for (int nt = 0; nt < 4; ++nt)
      bf[nt] = *(const bf16x8*)&sW[(wn + nt * 16 + lm) * 32 + quad * 8];
#pragma unroll
    for (int mt = 0; mt < 4; ++mt)
#pragma unroll
      for (int nt = 0; nt < 4; ++nt)
        acc[mt][nt] = __builtin_amdgcn_mfma_f32_16x16x32_bf16(af[mt], bf[nt], acc[mt][nt], 0, 0, 0);
  }

#pragma unroll
  for (int mt = 0; mt < 4; ++mt) {
#pragma unroll
    for (int r = 0; r < 4; ++r) {
      size_t row = row0 + wm + mt * 16 + quad * 4 + r;
      float kf = keepF ? keepF[row] : 1.f;
#pragma unroll
      for (int nt = 0; nt < 4; ++nt) {
        int col = col0 + wn + nt * 16 + lm;
        float v = acc[mt][nt][r] + bias[col];
        if (res) v += res[row * M + col];
        if (relu) v = fmaxf(v, 0.f);
        v *= kf;
        if (outF) outF[row * M + col] = v;
        if (outB) outB[row * M + col] = f2bf(v);
      }
    }
  }
}

// ---------------- MFMA sliding-window attention ----------------
// grid (L/64, H, B), block 256 (4 waves). Q/O stride 512; K/V stride 1024 (fused kv buffer).
// O may alias Q: block writes only its own 64 query rows / head cols, reads the same.
#define SQS 72   // sQ row stride (shorts), 16B aligned
#define SKS 72   // sK row stride
#define SVS 68   // sV row stride (8B aligned)
#define SPS 136  // sP row stride (16B aligned)
__global__ __launch_bounds__(256) void attn_kernel(const unsigned short* __restrict__ Q,
                                                   const unsigned short* __restrict__ K,
                                                   const unsigned short* __restrict__ V,
                                                   unsigned short* O) {
  __shared__ unsigned short smem[64 * SQS + 128 * SKS + 128 * SVS];  // 22528 shorts = 44 KB
  unsigned short* sQ = smem;                         // 64 x SQS
  unsigned short* sK = smem + 64 * SQS;              // 128 x SKS
  unsigned short* sV = smem + 64 * SQS + 128 * SKS;  // 128 x SVS
  unsigned short* sP = smem;                         // 64 x SPS, aliases sQ/sK (dead after scores)

  int i0 = blockIdx.x * 64;
  int h = blockIdx.y;
  int b = blockIdx.z;
  int tid = threadIdx.x;
  size_t qbase  = ((size_t)b * L_) * E_ + h * HD_;        // Q/O, row stride E_
  size_t kvbase = ((size_t)b * L_) * (2 * E_) + h * HD_;  // K, row stride 2*E_; V at +E_

  // stage Q: 64 rows x 64 d, uint4 chunks (8 shorts)
  for (int f = tid; f < 512; f += 256) {
    int r = f >> 3, c = f & 7;
    uint4 v = *(const uint4*)&Q[qbase + (size_t)(i0 + r) * E_ + c * 8];
    *(uint4*)&sQ[r * SQS + c * 8] = v;
  }
  // stage K: 128 rows (j = i0-64+r), zero-fill j<0
  for (int f = tid; f < 1024; f += 256) {
    int r = f >> 3, c = f & 7;
    int j = i0 - 64 + r;
    uint4 v = {0, 0, 0, 0};
    if (j >= 0) v = *(const uint4*)&K[kvbase + (size_t)j * (2 * E_) + c * 8];
    *(uint4*)&sK[r * SKS + c * 8] = v;
  }
  // stage V: uint2 chunks (4 shorts) since SVS*2 is only 8B aligned
  for (int f = tid; f < 2048; f += 256) {
    int r = f >> 4, c = f & 15;
    int j = i0 - 64 + r;
    uint2 v = {0, 0};
    if (j >= 0) v = *(const uint2*)&V[kvbase + E_ + (size_t)j * (2 * E_) + c * 4];
    *(uint2*)&sV[r * SVS + c * 4] = v;
  }
  __syncthreads();

  int wave = tid >> 6, lane = tid & 63;
  int lm = lane & 15, quad = lane >> 4;
  int wq = wave * 16;  // this wave's query row band

  // ---- scores: S[64 x 128] = Q @ K^T ----
  f32x4 accs[8];
  f32x4 z4 = {0.f, 0.f, 0.f, 0.f};
#pragma unroll
  for (int nt = 0; nt < 8; ++nt) accs[nt] = z4;
  bf16x8 aq0 = *(const bf16x8*)&sQ[(wq + lm) * SQS + quad * 8];
  bf16x8 aq1 = *(const bf16x8*)&sQ[(wq + lm) * SQS + 32 + quad * 8];
#pragma unroll
  for (int nt = 0; nt < 8; ++nt) {
    bf16x8 bk0 = *(const bf16x8*)&sK[(nt * 16 + lm) * SKS + quad * 8];
    bf16x8 bk1 = *(const bf16x8*)&sK[(nt * 16 + lm) * SKS + 32 + quad * 8];
    accs[nt] = __builtin_amdgcn_mfma_f32_16x16x32_bf16(aq0, bk0, accs[nt], 0, 0, 0);
    accs[nt] = __builtin_amdgcn_mfma_f32_16x16x32_bf16(aq1, bk1, accs[nt], 0, 0, 0);
  }
  __syncthreads();  // sQ/sK reads done; sP may now overwrite them

  // ---- mask + softmax in registers (row qi = wq + quad*4 + r; col jn = nt*16+lm) ----
#pragma unroll
  for (int r = 0; r < 4; ++r) {
    int qi = wq + quad * 4 + r;
    float sv[8];
    float mx = -INFINITY;
#pragma unroll
    for (int nt = 0; nt < 8; ++nt) {
      int jn = nt * 16 + lm;
      int d = qi + 64 - jn;       // i - j
      int j = i0 - 64 + jn;
      float s = (d >= 0 && d < WIN_ && j >= 0) ? accs[nt][r] * 0.125f : -INFINITY;
      sv[nt] = s;
      mx = fmaxf(mx, s);
    }
#pragma unroll
    for (int off = 1; off <= 8; off <<= 1) mx = fmaxf(mx, __shfl_xor(mx, off));
    float sum = 0.f;
#pragma unroll
    for (int nt = 0; nt < 8; ++nt) {
      float e = __expf(sv[nt] - mx);
      sv[nt] = e;
      sum += e;
    }
#pragma unroll
    for (int off = 1; off <= 8; off <<= 1) sum += __shfl_xor(sum, off);
    float inv = 1.f / sum;
#pragma unroll
    for (int nt = 0; nt < 8; ++nt) accs[nt][r] = sv[nt] * inv;
  }

  // ---- write P to LDS (C-layout -> A-layout round trip) ----
#pragma unroll
  for (int nt = 0; nt < 8; ++nt)
#pragma unroll
    for (int r = 0; r < 4; ++r)
      sP[(wq + quad * 4 + r) * SPS + nt * 16 + lm] = f2bf(accs[nt][r]);
  __syncthreads();

  // ---- O[64 x 64] = P @ V ----
  f32x4 acco[4];
#pragma unroll
  for (int nt = 0; nt < 4; ++nt) acco[nt] = z4;
#pragma unroll
  for (int kt = 0; kt < 4; ++kt) {
    bf16x8 ap = *(const bf16x8*)&sP[(wq + lm) * SPS + kt * 32 + quad * 8];
    int jb = kt * 32 + quad * 8;
#pragma unroll
    for (int nt = 0; nt < 4; ++nt) {
      union { unsigned short u[8]; bf16x8 v; } bv;
#pragma unroll
      for (int jj = 0; jj < 8; ++jj)
        bv.u[jj] = sV[(jb + jj) * SVS + nt * 16 + lm];
      acco[nt] = __builtin_amdgcn_mfma_f32_16x16x32_bf16(ap, bv.v, acco[nt], 0, 0, 0);
    }
  }
  // write O (bf16), C-layout
#pragma unroll
  for (int nt = 0; nt < 4; ++nt)
#pragma unroll
    for (int r = 0; r < 4; ++r) {
      int qi = wq + quad * 4 + r;
      O[qbase + (size_t)(i0 + qi) * E_ + nt * 16 + lm] = f2bf(acco[nt][r]);
    }
}

extern "C" void kernel_launch(void* const* d_in, const int* in_sizes, int n_in,
                              void* d_out, int out_size, void* d_ws, size_t ws_size,
                              hipStream_t stream) {
  const void*  tm    = d_in[0];
  const float* seqs  = (const float*)d_in[1];
  const float* w_in  = (const float*)d_in[2];
  const float* b_in  = (const float*)d_in[3];
  const float* w_out = (const float*)d_in[4];
  const float* b_out = (const float*)d_in[5];
  const float* ln1_g = (const float*)d_in[6];
  const float* ln1_b = (const float*)d_in[7];
  const float* ln2_g = (const float*)d_in[8];
  const float* ln2_b = (const float*)d_in[9];
  const float* c1_w  = (const float*)d_in[10];
  const float* c1_b  = (const float*)d_in[11];
  const float* c2_w  = (const float*)d_in[12];
  const float* c2_b  = (const float*)d_in[13];
  const float* lnf_g = (const float*)d_in[14];
  const float* lnf_b = (const float*)d_in[15];

  char* ws = (char*)d_ws;
  size_t off = 0;
  auto alloc = [&](size_t bytes) -> char* {
    char* p = ws + off;
    off += (bytes + 255) & ~(size_t)255;
    return p;
  };
  const size_t NE = (size_t)NROW * E_;
  float*          qin    = (float*)alloc(NE * 4);
  unsigned short* xb     = (unsigned short*)alloc(NE * 2);
  unsigned short* qinb   = (unsigned short*)alloc(NE * 2);
  unsigned short* qb     = (unsigned short*)alloc(NE * 2);
  unsigned short* kvb    = (unsigned short*)alloc(NE * 4);  // fused K|V, row stride 1024
  unsigned short* w_in_b = (unsigned short*)alloc((size_t)NB_ * 3 * E_ * E_ * 2);
  unsigned short* w_out_b= (unsigned short*)alloc((size_t)NB_ * E_ * E_ * 2);
  unsigned short* wc1b   = (unsigned short*)alloc((size_t)NB_ * E_ * E_ * 2);
  unsigned short* wc2b   = (unsigned short*)alloc((size_t)NB_ * E_ * E_ * 2);
  float*          keepF  = (float*)alloc((size_t)NROW * 4);
  int*            flag   = (int*)alloc(256);
  if (off > ws_size) return;  // fail loudly (output stays poisoned)

  // FFN hidden aliases kvb: K/V are dead after attn_kernel, hidden is produced
  // after it and consumed before the next block's KV projection.
  unsigned short* hb = kvb;

  float* x = (float*)d_out;  // fp32 activation lives in d_out

  detect_mask_kernel<<<1, 256, 0, stream>>>((const unsigned char*)tm, flag);
  expand_keep_kernel<<<NROW / 256, 256, 0, stream>>>(tm, flag, keepF);

  int n_win = NB_ * 3 * E_ * E_, n_sq = NB_ * E_ * E_;
  f2bf_kernel<<<(n_win + 255) / 256, 256, 0, stream>>>(w_in, w_in_b, n_win);
  f2bf_kernel<<<(n_sq + 255) / 256, 256, 0, stream>>>(w_out, w_out_b, n_sq);
  f2bf_kernel<<<(n_sq + 255) / 256, 256, 0, stream>>>(c1_w, wc1b, n_sq);
  f2bf_kernel<<<(n_sq + 255) / 256, 256, 0, stream>>>(c2_w, wc2b, n_sq);

  mask_kernel<<<(int)(NE / 4 / 256), 256, 0, stream>>>(seqs, keepF, x, xb);

  dim3 ggrid(E_ / 128, NROW / 128);
  dim3 ggridKV(2 * E_ / 128, NROW / 128);
  for (int blk = 0; blk < NB_; ++blk) {
    const unsigned short* wq = w_in_b + (size_t)blk * 3 * E_ * E_;
    const unsigned short* wkv = wq + (size_t)E_ * E_;  // wk || wv contiguous
    const float* bq = b_in + (size_t)blk * 3 * E_;
    const float* bkv = bq + E_;

    // q_in = LN(x, ln1)
    ln_kernel<<<NROW / 4, 256, 0, stream>>>(x, ln1_g + blk * E_, ln1_b + blk * E_, qin, qinb);
    // q projection (bf16 out), fused k|v projection (M=1024)
    gemm_kernel<<<ggrid, 256, 0, stream>>>(qinb, wq, bq, nullptr, nullptr, nullptr, qb, E_, E_, 0);
    gemm_kernel<<<ggridKV, 256, 0, stream>>>(xb, wkv, bkv, nullptr, nullptr, nullptr, kvb, E_, 2 * E_, 0);
    // windowed MFMA attention, O overwrites qb
    attn_kernel<<<dim3(L_ / 64, H_, B_), 256, 0, stream>>>(qb, kvb, kvb, qb);
    // x = qin + attnO @ w_out^T + b_out  (fp32 into d_out)
    gemm_kernel<<<ggrid, 256, 0, stream>>>(qb, w_out_b + (size_t)blk * E_ * E_,
                                           b_out + blk * E_, qin, nullptr, x, nullptr, E_, E_, 0);
    // x = LN(x, ln2) in place + bf16 copy
    ln_kernel<<<NROW / 4, 256, 0, stream>>>(x, ln2_g + blk * E_, ln2_b + blk * E_, x, xb);
    // h = relu(x @ c1^T + b1)  (bf16, into kvb alias)
    gemm_kernel<<<ggrid, 256, 0, stream>>>(xb, wc1b + (size_t)blk * E_ * E_,
                                           c1_b + blk * E_, nullptr, nullptr, nullptr, hb, E_, E_, 1);
    // x = (h @ c2^T + b2 + x) * keep   (fp32 into d_out, bf16 into xb)
    gemm_kernel<<<ggrid, 256, 0, stream>>>(hb, wc2b + (size_t)blk * E_ * E_,
                                           c2_b + blk * E_, x, keepF, x, xb, E_, E_, 0);
  }
  // final LN in place on d_out
  ln_kernel<<<NROW / 4, 256, 0, stream>>>(x, lnf_g, lnf_b, x, nullptr);
}

// Round 4
// 1666.026 us; speedup vs baseline: 2.6115x; 1.2844x over previous
//
#include <hip/hip_runtime.h>
#include <cstdint>

#define B_   128
#define L_   512
#define E_   512
#define H_   8
#define HD_  64
#define NB_  2
#define WIN_ 64
#define NROW (B_ * L_)  // 65536

typedef __attribute__((ext_vector_type(8))) __bf16 bf16x8;
typedef __attribute__((ext_vector_type(4))) float f32x4;

static __device__ __forceinline__ unsigned short f2bf(float f) {
  union { float f; unsigned int u; } c; c.f = f;
  unsigned int u = c.u;
  unsigned int r = (u + 0x7fffu + ((u >> 16) & 1u)) >> 16;
  return (unsigned short)r;
}
static __device__ __forceinline__ float bf2f(unsigned short s) {
  union { unsigned int u; float f; } c; c.u = ((unsigned int)s) << 16; return c.f;
}

static __device__ __forceinline__ void gld_lds16(const unsigned short* g, unsigned short* l) {
  __builtin_amdgcn_global_load_lds((const __attribute__((address_space(1))) void*)g,
                                   (__attribute__((address_space(3))) void*)l, 16, 0, 0);
}

// ---------------- mask dtype detection (bool-bytes vs int32) ----------------
__global__ void detect_mask_kernel(const unsigned char* tm, int* flag) {
  __shared__ int f;
  if (threadIdx.x == 0) f = 0;
  __syncthreads();
  int local = 0;
  for (int i = threadIdx.x; i < NROW; i += blockDim.x)
    if ((i & 3) && tm[i]) local = 1;
  if (local) atomicOr(&f, 1);
  __syncthreads();
  if (threadIdx.x == 0) *flag = f;  // 1 => uint8 bytes, 0 => int32
}

__global__ void expand_keep_kernel(const void* tmv, const int* flag, float* keepF) {
  int i = blockIdx.x * blockDim.x + threadIdx.x;
  if (i >= NROW) return;
  int m;
  if (*flag) m = ((const unsigned char*)tmv)[i] != 0;
  else       m = ((const int*)tmv)[i] != 0;
  keepF[i] = m ? 0.f : 1.f;
}

// ---------------- fp32 -> bf16 weight conversion ----------------
__global__ void f2bf_kernel(const float* __restrict__ in, unsigned short* __restrict__ out, int n) {
  int i = blockIdx.x * blockDim.x + threadIdx.x;
  if (i < n) out[i] = f2bf(in[i]);
}

// ---------------- x = seqs * keep (bf16 out only) ----------------
__global__ void mask_kernel(const float* __restrict__ seqs, const float* __restrict__ keepF,
                            unsigned short* __restrict__ xB) {
  int i = blockIdx.x * blockDim.x + threadIdx.x;  // group of 4 elements
  int idx = i * 4;
  int row = idx >> 9;  // / E_
  float k = keepF[row];
  float4 v = *(const float4*)(seqs + idx);
  ushort4 b;
  b.x = f2bf(v.x * k); b.y = f2bf(v.y * k); b.z = f2bf(v.z * k); b.w = f2bf(v.w * k);
  *(ushort4*)(xB + idx) = b;
}

// ---------------- LayerNorm over E=512, bf16 in, one wave per row ----------------
__global__ __launch_bounds__(256) void ln_kernel(const unsigned short* __restrict__ X,
                                                 const float* __restrict__ g,
                                                 const float* __restrict__ bb,
                                                 unsigned short* outB, float* outF) {
  int wave = threadIdx.x >> 6, lane = threadIdx.x & 63;
  size_t row = (size_t)blockIdx.x * 4 + wave;
  const unsigned short* xr = X + row * E_;
  int e0 = lane * 8;
  union { uint4 q; unsigned short s[8]; } raw;
  raw.q = *(const uint4*)(xr + e0);
  float v[8];
#pragma unroll
  for (int i = 0; i < 8; ++i) v[i] = bf2f(raw.s[i]);
  float s = 0.f, s2 = 0.f;
#pragma unroll
  for (int i = 0; i < 8; ++i) { s += v[i]; s2 += v[i] * v[i]; }
  for (int off = 32; off; off >>= 1) { s += __shfl_xor(s, off); s2 += __shfl_xor(s2, off); }
  float mean = s * (1.f / E_);
  float var  = s2 * (1.f / E_) - mean * mean;
  float rs = rsqrtf(var + 1e-8f);
  float4 g0 = *(const float4*)(g + e0),  g1 = *(const float4*)(g + e0 + 4);
  float4 b0 = *(const float4*)(bb + e0), b1 = *(const float4*)(bb + e0 + 4);
  float gg[8] = {g0.x, g0.y, g0.z, g0.w, g1.x, g1.y, g1.z, g1.w};
  float bv[8] = {b0.x, b0.y, b0.z, b0.w, b1.x, b1.y, b1.z, b1.w};
  float y[8];
#pragma unroll
  for (int i = 0; i < 8; ++i) y[i] = (v[i] - mean) * rs * gg[i] + bv[i];
  if (outB) {
    union { uint4 q; unsigned short s[8]; } pk;
#pragma unroll
    for (int i = 0; i < 8; ++i) pk.s[i] = f2bf(y[i]);
    *(uint4*)(outB + row * E_ + e0) = pk.q;
  }
  if (outF) {
    float4 y0 = {y[0], y[1], y[2], y[3]}, y1 = {y[4], y[5], y[6], y[7]};
    *(float4*)(outF + row * E_ + e0) = y0;
    *(float4*)(outF + row * E_ + e0 + 4) = y1;
  }
}

// ---------------- bf16 MFMA GEMM: C[N x M] = A[N x K] @ W[M x K]^T + epilogue ----
// 128x128 tile, BK=64 as two BK=32 half-tiles (4 x 8KB LDS arrays keeps the
// proven bank pattern AND the global_load_lds contiguity requirement).
__global__ __launch_bounds__(256) void gemm_kernel(
    const unsigned short* __restrict__ A, const unsigned short* __restrict__ W,
    const float* __restrict__ bias, const unsigned short* res, const float* __restrict__ keepF,
    unsigned short* outB, int K, int M, int relu) {
  __shared__ unsigned short sA0[128 * 32];
  __shared__ unsigned short sA1[128 * 32];
  __shared__ unsigned short sW0[128 * 32];
  __shared__ unsigned short sW1[128 * 32];
  int tid = threadIdx.x;
  int wave = tid >> 6, lane = tid & 63;
  int lm = lane & 15, quad = lane >> 4;
  size_t row0 = (size_t)blockIdx.y * 128;
  int col0 = blockIdx.x * 128;
  int wm = (wave >> 1) * 64, wn = (wave & 1) * 64;

  f32x4 acc[4][4];
  f32x4 z = {0.f, 0.f, 0.f, 0.f};
#pragma unroll
  for (int i = 0; i < 4; ++i)
#pragma unroll
    for (int j = 0; j < 4; ++j) acc[i][j] = z;

  // staging: instr a covers rows 0..63 (16 rows/wave), instr b rows 64..127
  int ar0 = tid >> 2, ak0 = (tid & 3) * 8;
  int ar1 = ar0 + 64;
  unsigned short* dA0a = &sA0[(wave * 16) * 32];
  unsigned short* dA0b = &sA0[(wave * 16 + 64) * 32];
  unsigned short* dA1a = &sA1[(wave * 16) * 32];
  unsigned short* dA1b = &sA1[(wave * 16 + 64) * 32];
  unsigned short* dW0a = &sW0[(wave * 16) * 32];
  unsigned short* dW0b = &sW0[(wave * 16 + 64) * 32];
  unsigned short* dW1a = &sW1[(wave * 16) * 32];
  unsigned short* dW1b = &sW1[(wave * 16 + 64) * 32];
  const unsigned short* Ar0 = A + (row0 + ar0) * K + ak0;
  const unsigned short* Ar1 = A + (row0 + ar1) * K + ak0;
  const unsigned short* Wr0 = W + (size_t)(col0 + ar0) * K + ak0;
  const unsigned short* Wr1 = W + (size_t)(col0 + ar1) * K + ak0;

  for (int k0 = 0; k0 < K; k0 += 64) {
    __syncthreads();
    gld_lds16(Ar0 + k0,      dA0a);
    gld_lds16(Ar1 + k0,      dA0b);
    gld_lds16(Ar0 + k0 + 32, dA1a);
    gld_lds16(Ar1 + k0 + 32, dA1b);
    gld_lds16(Wr0 + k0,      dW0a);
    gld_lds16(Wr1 + k0,      dW0b);
    gld_lds16(Wr0 + k0 + 32, dW1a);
    gld_lds16(Wr1 + k0 + 32, dW1b);
    __syncthreads();
    bf16x8 a0[4], a1[4], b0[4], b1[4];
#pragma unroll
    for (int mt = 0; mt < 4; ++mt) {
      a0[mt] = *(const bf16x8*)&sA0[(wm + mt * 16 + lm) * 32 + quad * 8];
      a1[mt] = *(const bf16x8*)&sA1[(wm + mt * 16 + lm) * 32 + quad * 8];
    }
#pragma unroll
    for (int nt = 0; nt < 4; ++nt) {
      b0[nt] = *(const bf16x8*)&sW0[(wn + nt * 16 + lm) * 32 + quad * 8];
      b1[nt] = *(const bf16x8*)&sW1[(wn + nt * 16 + lm) * 32 + quad * 8];
    }
#pragma unroll
    for (int mt = 0; mt < 4; ++mt)
#pragma unroll
      for (int nt = 0; nt < 4; ++nt) {
        acc[mt][nt] = __builtin_amdgcn_mfma_f32_16x16x32_bf16(a0[mt], b0[nt], acc[mt][nt], 0, 0, 0);
        acc[mt][nt] = __builtin_amdgcn_mfma_f32_16x16x32_bf16(a1[mt], b1[nt], acc[mt][nt], 0, 0, 0);
      }
  }

#pragma unroll
  for (int mt = 0; mt < 4; ++mt) {
#pragma unroll
    for (int r = 0; r < 4; ++r) {
      size_t row = row0 + wm + mt * 16 + quad * 4 + r;
      float kf = keepF ? keepF[row] : 1.f;
#pragma unroll
      for (int nt = 0; nt < 4; ++nt) {
        int col = col0 + wn + nt * 16 + lm;
        float v = acc[mt][nt][r] + bias[col];
        if (res) v += bf2f(res[row * M + col]);
        if (relu) v = fmaxf(v, 0.f);
        v *= kf;
        outB[row * M + col] = f2bf(v);
      }
    }
  }
}

// ---------------- MFMA sliding-window attention ----------------
// grid (L/64, H, B), block 256 (4 waves). Q/O stride 512; K/V stride 1024 (fused kv buffer).
// O may alias Q: block writes only its own 64 query rows / head cols, reads the same.
#define SQS 72   // sQ row stride (shorts), 16B aligned
#define SKS 72   // sK row stride
#define SVS 68   // sV row stride (8B aligned)
#define SPS 136  // sP row stride (16B aligned)
__global__ __launch_bounds__(256) void attn_kernel(const unsigned short* __restrict__ Q,
                                                   const unsigned short* __restrict__ K,
                                                   const unsigned short* __restrict__ V,
                                                   unsigned short* O) {
  __shared__ unsigned short smem[64 * SQS + 128 * SKS + 128 * SVS];  // 44 KB
  unsigned short* sQ = smem;                         // 64 x SQS
  unsigned short* sK = smem + 64 * SQS;              // 128 x SKS
  unsigned short* sV = smem + 64 * SQS + 128 * SKS;  // 128 x SVS
  unsigned short* sP = smem;                         // 64 x SPS, aliases sQ/sK (dead after scores)

  int i0 = blockIdx.x * 64;
  int h = blockIdx.y;
  int b = blockIdx.z;
  int tid = threadIdx.x;
  size_t qbase  = ((size_t)b * L_) * E_ + h * HD_;        // Q/O, row stride E_
  size_t kvbase = ((size_t)b * L_) * (2 * E_) + h * HD_;  // K, row stride 2*E_; V at +E_

  for (int f = tid; f < 512; f += 256) {
    int r = f >> 3, c = f & 7;
    uint4 v = *(const uint4*)&Q[qbase + (size_t)(i0 + r) * E_ + c * 8];
    *(uint4*)&sQ[r * SQS + c * 8] = v;
  }
  for (int f = tid; f < 1024; f += 256) {
    int r = f >> 3, c = f & 7;
    int j = i0 - 64 + r;
    uint4 v = {0, 0, 0, 0};
    if (j >= 0) v = *(const uint4*)&K[kvbase + (size_t)j * (2 * E_) + c * 8];
    *(uint4*)&sK[r * SKS + c * 8] = v;
  }
  for (int f = tid; f < 2048; f += 256) {
    int r = f >> 4, c = f & 15;
    int j = i0 - 64 + r;
    uint2 v = {0, 0};
    if (j >= 0) v = *(const uint2*)&V[kvbase + E_ + (size_t)j * (2 * E_) + c * 4];
    *(uint2*)&sV[r * SVS + c * 4] = v;
  }
  __syncthreads();

  int wave = tid >> 6, lane = tid & 63;
  int lm = lane & 15, quad = lane >> 4;
  int wq = wave * 16;

  // ---- scores: S[64 x 128] = Q @ K^T ----
  f32x4 accs[8];
  f32x4 z4 = {0.f, 0.f, 0.f, 0.f};
#pragma unroll
  for (int nt = 0; nt < 8; ++nt) accs[nt] = z4;
  bf16x8 aq0 = *(const bf16x8*)&sQ[(wq + lm) * SQS + quad * 8];
  bf16x8 aq1 = *(const bf16x8*)&sQ[(wq + lm) * SQS + 32 + quad * 8];
#pragma unroll
  for (int nt = 0; nt < 8; ++nt) {
    bf16x8 bk0 = *(const bf16x8*)&sK[(nt * 16 + lm) * SKS + quad * 8];
    bf16x8 bk1 = *(const bf16x8*)&sK[(nt * 16 + lm) * SKS + 32 + quad * 8];
    accs[nt] = __builtin_amdgcn_mfma_f32_16x16x32_bf16(aq0, bk0, accs[nt], 0, 0, 0);
    accs[nt] = __builtin_amdgcn_mfma_f32_16x16x32_bf16(aq1, bk1, accs[nt], 0, 0, 0);
  }
  __syncthreads();

  // ---- mask + softmax in registers ----
#pragma unroll
  for (int r = 0; r < 4; ++r) {
    int qi = wq + quad * 4 + r;
    float sv[8];
    float mx = -INFINITY;
#pragma unroll
    for (int nt = 0; nt < 8; ++nt) {
      int jn = nt * 16 + lm;
      int d = qi + 64 - jn;
      int j = i0 - 64 + jn;
      float s = (d >= 0 && d < WIN_ && j >= 0) ? accs[nt][r] * 0.125f : -INFINITY;
      sv[nt] = s;
      mx = fmaxf(mx, s);
    }
#pragma unroll
    for (int off = 1; off <= 8; off <<= 1) mx = fmaxf(mx, __shfl_xor(mx, off));
    float sum = 0.f;
#pragma unroll
    for (int nt = 0; nt < 8; ++nt) {
      float e = __expf(sv[nt] - mx);
      sv[nt] = e;
      sum += e;
    }
#pragma unroll
    for (int off = 1; off <= 8; off <<= 1) sum += __shfl_xor(sum, off);
    float inv = 1.f / sum;
#pragma unroll
    for (int nt = 0; nt < 8; ++nt) accs[nt][r] = sv[nt] * inv;
  }

  // ---- write P to LDS (C-layout -> A-layout round trip) ----
#pragma unroll
  for (int nt = 0; nt < 8; ++nt)
#pragma unroll
    for (int r = 0; r < 4; ++r)
      sP[(wq + quad * 4 + r) * SPS + nt * 16 + lm] = f2bf(accs[nt][r]);
  __syncthreads();

  // ---- O[64 x 64] = P @ V ----
  f32x4 acco[4];
#pragma unroll
  for (int nt = 0; nt < 4; ++nt) acco[nt] = z4;
#pragma unroll
  for (int kt = 0; kt < 4; ++kt) {
    bf16x8 ap = *(const bf16x8*)&sP[(wq + lm) * SPS + kt * 32 + quad * 8];
    int jb = kt * 32 + quad * 8;
#pragma unroll
    for (int nt = 0; nt < 4; ++nt) {
      union { unsigned short u[8]; bf16x8 v; } bv;
#pragma unroll
      for (int jj = 0; jj < 8; ++jj)
        bv.u[jj] = sV[(jb + jj) * SVS + nt * 16 + lm];
      acco[nt] = __builtin_amdgcn_mfma_f32_16x16x32_bf16(ap, bv.v, acco[nt], 0, 0, 0);
    }
  }
#pragma unroll
  for (int nt = 0; nt < 4; ++nt)
#pragma unroll
    for (int r = 0; r < 4; ++r) {
      int qi = wq + quad * 4 + r;
      O[qbase + (size_t)(i0 + qi) * E_ + nt * 16 + lm] = f2bf(acco[nt][r]);
    }
}

extern "C" void kernel_launch(void* const* d_in, const int* in_sizes, int n_in,
                              void* d_out, int out_size, void* d_ws, size_t ws_size,
                              hipStream_t stream) {
  const void*  tm    = d_in[0];
  const float* seqs  = (const float*)d_in[1];
  const float* w_in  = (const float*)d_in[2];
  const float* b_in  = (const float*)d_in[3];
  const float* w_out = (const float*)d_in[4];
  const float* b_out = (const float*)d_in[5];
  const float* ln1_g = (const float*)d_in[6];
  const float* ln1_b = (const float*)d_in[7];
  const float* ln2_g = (const float*)d_in[8];
  const float* ln2_b = (const float*)d_in[9];
  const float* c1_w  = (const float*)d_in[10];
  const float* c1_b  = (const float*)d_in[11];
  const float* c2_w  = (const float*)d_in[12];
  const float* c2_b  = (const float*)d_in[13];
  const float* lnf_g = (const float*)d_in[14];
  const float* lnf_b = (const float*)d_in[15];

  char* ws = (char*)d_ws;
  size_t off = 0;
  auto alloc = [&](size_t bytes) -> char* {
    char* p = ws + off;
    off += (bytes + 255) & ~(size_t)255;
    return p;
  };
  const size_t NE = (size_t)NROW * E_;
  unsigned short* xb     = (unsigned short*)alloc(NE * 2);
  unsigned short* qinb   = (unsigned short*)alloc(NE * 2);
  unsigned short* qb     = (unsigned short*)alloc(NE * 2);
  unsigned short* kvb    = (unsigned short*)alloc(NE * 4);  // fused K|V, row stride 1024
  unsigned short* w_in_b = (unsigned short*)alloc((size_t)NB_ * 3 * E_ * E_ * 2);
  unsigned short* w_out_b= (unsigned short*)alloc((size_t)NB_ * E_ * E_ * 2);
  unsigned short* wc1b   = (unsigned short*)alloc((size_t)NB_ * E_ * E_ * 2);
  unsigned short* wc2b   = (unsigned short*)alloc((size_t)NB_ * E_ * E_ * 2);
  float*          keepF  = (float*)alloc((size_t)NROW * 4);
  int*            flag   = (int*)alloc(256);
  if (off > ws_size) return;  // fail loudly (output stays poisoned)

  // FFN hidden aliases kvb: K/V dead after attn; hidden consumed before next KV proj.
  unsigned short* hb = kvb;

  detect_mask_kernel<<<1, 256, 0, stream>>>((const unsigned char*)tm, flag);
  expand_keep_kernel<<<NROW / 256, 256, 0, stream>>>(tm, flag, keepF);

  int n_win = NB_ * 3 * E_ * E_, n_sq = NB_ * E_ * E_;
  f2bf_kernel<<<(n_win + 255) / 256, 256, 0, stream>>>(w_in, w_in_b, n_win);
  f2bf_kernel<<<(n_sq + 255) / 256, 256, 0, stream>>>(w_out, w_out_b, n_sq);
  f2bf_kernel<<<(n_sq + 255) / 256, 256, 0, stream>>>(c1_w, wc1b, n_sq);
  f2bf_kernel<<<(n_sq + 255) / 256, 256, 0, stream>>>(c2_w, wc2b, n_sq);

  mask_kernel<<<(int)(NE / 4 / 256), 256, 0, stream>>>(seqs, keepF, xb);

  dim3 ggrid(E_ / 128, NROW / 128);
  dim3 ggridKV(2 * E_ / 128, NROW / 128);
  for (int blk = 0; blk < NB_; ++blk) {
    const unsigned short* wq = w_in_b + (size_t)blk * 3 * E_ * E_;
    const unsigned short* wkv = wq + (size_t)E_ * E_;  // wk || wv contiguous
    const float* bq = b_in + (size_t)blk * 3 * E_;
    const float* bkv = bq + E_;

    // q_in = LN(x, ln1) -> qinb (bf16)
    ln_kernel<<<NROW / 4, 256, 0, stream>>>(xb, ln1_g + blk * E_, ln1_b + blk * E_, qinb, nullptr);
    // q projection; fused k|v projection (M=1024)
    gemm_kernel<<<ggrid, 256, 0, stream>>>(qinb, wq, bq, nullptr, nullptr, qb, E_, E_, 0);
    gemm_kernel<<<ggridKV, 256, 0, stream>>>(xb, wkv, bkv, nullptr, nullptr, kvb, E_, 2 * E_, 0);
    // windowed MFMA attention, O overwrites qb
    attn_kernel<<<dim3(L_ / 64, H_, B_), 256, 0, stream>>>(qb, kvb, kvb, qb);
    // x = qinb + attnO @ w_out^T + b_out  (bf16 into xb; old xb fully consumed)
    gemm_kernel<<<ggrid, 256, 0, stream>>>(qb, w_out_b + (size_t)blk * E_ * E_,
                                           b_out + blk * E_, qinb, nullptr, xb, E_, E_, 0);
    // x = LN(x, ln2) in place (bf16)
    ln_kernel<<<NROW / 4, 256, 0, stream>>>(xb, ln2_g + blk * E_, ln2_b + blk * E_, xb, nullptr);
    // h = relu(x @ c1^T + b1)
    gemm_kernel<<<ggrid, 256, 0, stream>>>(xb, wc1b + (size_t)blk * E_ * E_,
                                           c1_b + blk * E_, nullptr, nullptr, hb, E_, E_, 1);
    // x = (h @ c2^T + b2 + x) * keep  (bf16 into xb; res==out is safe: per-element read-then-write)
    gemm_kernel<<<ggrid, 256, 0, stream>>>(hb, wc2b + (size_t)blk * E_ * E_,
                                           c2_b + blk * E_, xb, keepF, xb, E_, E_, 0);
  }
  // final LN: bf16 in -> fp32 d_out
  ln_kernel<<<NROW / 4, 256, 0, stream>>>(xb, lnf_g, lnf_b, nullptr, (float*)d_out);
}